// Round 1
// baseline (1761.645 us; speedup 1.0000x reference)
//
#include <hip/hip_runtime.h>
#include <math.h>

#define BB 2
#define SS 2048
#define DD 1024
#define HH 16
#define HDD 64

// ---------------------------------------------------------------------------
// Tiled fp32 GEMM: C = A[M,K] @ W[K,N] (+ bias).  A, W row-major.
// LAYOUT 0: C row-major [M,N]
// LAYOUT 1: scatter to [B,H,S,HD]:  m = b*S+s, n = h*HD+hd
// ---------------------------------------------------------------------------
template<int LAYOUT>
__global__ __launch_bounds__(256) void gemm_f32_64x64(
    const float* __restrict__ A, const float* __restrict__ W,
    const float* __restrict__ bias, float* __restrict__ C,
    int M, int N, int K)
{
    const int bm = blockIdx.x;
    const int bn = blockIdx.y;
    const int tid = threadIdx.x;
    const int tx = tid & 15;   // col group 0..15
    const int ty = tid >> 4;   // row group 0..15

    __shared__ float As[64][17];   // [m][k], padded: stride 17 floats
    __shared__ float Bs[16][64];   // [k][n]

    float acc[4][4] = {};

    const int m0 = bm * 64;
    const int n0 = bn * 64;

    for (int k0 = 0; k0 < K; k0 += 16) {
        // A tile 64x16: thread t -> row t/4, cols (t%4)*4 (float4)
        {
            const int r = tid >> 2;
            const int c = (tid & 3) * 4;
            const float4 v = *reinterpret_cast<const float4*>(
                &A[(size_t)(m0 + r) * K + k0 + c]);
            As[r][c + 0] = v.x; As[r][c + 1] = v.y;
            As[r][c + 2] = v.z; As[r][c + 3] = v.w;
        }
        // W tile 16x64: thread t -> row t/16, cols (t%16)*4 (float4)
        {
            const int r = tid >> 4;
            const int c = (tid & 15) * 4;
            const float4 v = *reinterpret_cast<const float4*>(
                &W[(size_t)(k0 + r) * N + n0 + c]);
            *reinterpret_cast<float4*>(&Bs[r][c]) = v;
        }
        __syncthreads();
        #pragma unroll
        for (int kk = 0; kk < 16; ++kk) {
            float a[4], b[4];
            #pragma unroll
            for (int i = 0; i < 4; ++i) a[i] = As[ty * 4 + i][kk];
            #pragma unroll
            for (int j = 0; j < 4; ++j) b[j] = Bs[kk][tx * 4 + j];
            #pragma unroll
            for (int i = 0; i < 4; ++i)
                #pragma unroll
                for (int j = 0; j < 4; ++j)
                    acc[i][j] += a[i] * b[j];
        }
        __syncthreads();
    }

    #pragma unroll
    for (int i = 0; i < 4; ++i) {
        const int m = m0 + ty * 4 + i;
        #pragma unroll
        for (int j = 0; j < 4; ++j) {
            const int n = n0 + tx * 4 + j;
            float v = acc[i][j];
            if (bias) v += bias[n];
            if (LAYOUT == 0) {
                C[(size_t)m * N + n] = v;
            } else {
                const int b_ = m / SS, s_ = m % SS;
                const int h_ = n / HDD, d_ = n % HDD;
                C[(((size_t)(b_ * HH + h_) * SS) + s_) * HDD + d_] = v;
            }
        }
    }
}

// ---------------------------------------------------------------------------
// Causal flash attention with ALiBi (key-position bias), fp32.
// Q,K,V in [B,H,S,HD]; Out in [B,S,D] (= [B,S,H*HD]).
// Block: 256 thr = 4 waves; block owns 64 query rows of one (b,h).
// Wave w owns rows w*16..w*16+15. Score phase: lane = key j in 64-tile.
// PV phase: lane = dim d. Online softmax, masked scores -> -3e38 -> p==0.
// ---------------------------------------------------------------------------
__global__ __launch_bounds__(256) void attn_flash_f32(
    const float* __restrict__ Q, const float* __restrict__ K,
    const float* __restrict__ V, float* __restrict__ Out)
{
    const int qt = blockIdx.x;            // query tile 0..S/64-1
    const int bh = blockIdx.y;            // 0..B*H-1
    const int b  = bh / HH, h = bh % HH;
    const int tid  = threadIdx.x;
    const int wave = tid >> 6;            // 0..3
    const int lane = tid & 63;

    __shared__ float Qs[64][65];
    __shared__ float Ks[64][65];
    __shared__ float Vs[64][65];
    __shared__ float Ps[4][16][64];

    const float slope = exp2f(-0.5f * (float)(h + 1));  // 2^(-8*(h+1)/16)
    const float scale = 0.125f;                          // 1/sqrt(64)

    // load Q block (64 rows x 64 dims)
    const size_t baseQ = ((size_t)bh * SS + (size_t)qt * 64) * HDD;
    {
        const int r = tid >> 4;           // 0..15
        const int c = (tid & 15) * 4;
        #pragma unroll
        for (int it = 0; it < 4; ++it) {
            const int rr = it * 16 + r;
            const float4 v = *reinterpret_cast<const float4*>(
                &Q[baseQ + (size_t)rr * HDD + c]);
            Qs[rr][c + 0] = v.x; Qs[rr][c + 1] = v.y;
            Qs[rr][c + 2] = v.z; Qs[rr][c + 3] = v.w;
        }
    }

    float m[16], l[16], o[16];
    #pragma unroll
    for (int i = 0; i < 16; ++i) { m[i] = -3.0e38f; l[i] = 0.0f; o[i] = 0.0f; }

    const int row0 = wave * 16;
    const int ig0  = qt * 64;

    for (int kt = 0; kt <= qt; ++kt) {
        __syncthreads();   // previous iteration's PV / Q-load done
        // load K,V tiles (64x64 each)
        {
            const size_t baseK = ((size_t)bh * SS + (size_t)kt * 64) * HDD;
            const int r = tid >> 4;
            const int c = (tid & 15) * 4;
            #pragma unroll
            for (int it = 0; it < 4; ++it) {
                const int rr = it * 16 + r;
                const float4 vk = *reinterpret_cast<const float4*>(
                    &K[baseK + (size_t)rr * HDD + c]);
                Ks[rr][c + 0] = vk.x; Ks[rr][c + 1] = vk.y;
                Ks[rr][c + 2] = vk.z; Ks[rr][c + 3] = vk.w;
                const float4 vv = *reinterpret_cast<const float4*>(
                    &V[baseK + (size_t)rr * HDD + c]);
                Vs[rr][c + 0] = vv.x; Vs[rr][c + 1] = vv.y;
                Vs[rr][c + 2] = vv.z; Vs[rr][c + 3] = vv.w;
            }
        }
        __syncthreads();

        // scores: s[i] = Q[row0+i] . K[lane]
        float s[16];
        #pragma unroll
        for (int i = 0; i < 16; ++i) s[i] = 0.0f;
        #pragma unroll 4
        for (int d = 0; d < 64; ++d) {
            const float kd = Ks[lane][d];
            #pragma unroll
            for (int i = 0; i < 16; ++i)
                s[i] += Qs[row0 + i][d] * kd;
        }

        const int jg = kt * 64 + lane;
        const float ab = slope * (float)jg;

        #pragma unroll
        for (int i = 0; i < 16; ++i) {
            const int ig = ig0 + row0 + i;
            float si = s[i] * scale - ab;
            if (jg > ig) si = -3.0e38f;     // causal: exp underflows to 0,
                                            // matching reference's -1e9 mask
            float mx = si;
            #pragma unroll
            for (int off = 32; off; off >>= 1)
                mx = fmaxf(mx, __shfl_xor(mx, off, 64));
            const float mnew = fmaxf(m[i], mx);
            const float p    = __expf(si - mnew);
            const float corr = __expf(m[i] - mnew);
            float ps = p;
            #pragma unroll
            for (int off = 32; off; off >>= 1)
                ps += __shfl_xor(ps, off, 64);
            l[i] = l[i] * corr + ps;
            o[i] *= corr;
            m[i] = mnew;
            Ps[wave][i][lane] = p;
        }
        __syncthreads();

        // PV: lane = dim d;  o[i] += sum_j P[i][j] * V[j][d]
        #pragma unroll 4
        for (int j = 0; j < 64; ++j) {
            const float vj = Vs[j][lane];
            #pragma unroll
            for (int i = 0; i < 16; ++i)
                o[i] += Ps[wave][i][j] * vj;
        }
    }

    // normalize + write to [B,S,D]
    #pragma unroll
    for (int i = 0; i < 16; ++i) {
        const int srow = qt * 64 + row0 + i;
        const float val = o[i] / l[i];
        Out[((size_t)b * SS + srow) * DD + h * HDD + lane] = val;
    }
}

// ---------------------------------------------------------------------------
extern "C" void kernel_launch(void* const* d_in, const int* in_sizes, int n_in,
                              void* d_out, int out_size, void* d_ws, size_t ws_size,
                              hipStream_t stream) {
    const float* x  = (const float*)d_in[0];
    const float* Wq = (const float*)d_in[1];
    const float* bq = (const float*)d_in[2];
    const float* Wk = (const float*)d_in[3];
    const float* bk = (const float*)d_in[4];
    const float* Wv = (const float*)d_in[5];
    const float* Wo = (const float*)d_in[6];
    const float* bo = (const float*)d_in[7];
    float* out = (float*)d_out;

    const size_t per = (size_t)BB * HH * SS * HDD;  // 4,194,304 floats
    float* Qb   = (float*)d_ws;
    float* Kb   = Qb + per;
    float* Vb   = Kb + per;
    float* attn = Vb + per;   // [B,S,D]

    const dim3 blk(256);
    const dim3 gProj(BB * SS / 64, DD / 64);   // 64 x 16

    gemm_f32_64x64<1><<<gProj, blk, 0, stream>>>(x, Wq, bq,      Qb, BB * SS, DD, DD);
    gemm_f32_64x64<1><<<gProj, blk, 0, stream>>>(x, Wk, bk,      Kb, BB * SS, DD, DD);
    gemm_f32_64x64<1><<<gProj, blk, 0, stream>>>(x, Wv, nullptr, Vb, BB * SS, DD, DD);

    const dim3 gAttn(SS / 64, BB * HH);        // 32 x 32
    attn_flash_f32<<<gAttn, blk, 0, stream>>>(Qb, Kb, Vb, attn);

    gemm_f32_64x64<0><<<gProj, blk, 0, stream>>>(attn, Wo, bo, out, BB * SS, DD, DD);
}

// Round 2
// 733.052 us; speedup vs baseline: 2.4032x; 2.4032x over previous
//
#include <hip/hip_runtime.h>
#include <math.h>

#define BB 2
#define SS 2048
#define DD 1024
#define HH 16
#define HDD 64

typedef __attribute__((ext_vector_type(4))) short short4v;
typedef __attribute__((ext_vector_type(8))) short short8v;
typedef __attribute__((ext_vector_type(4))) float f32x4;

__device__ inline unsigned short f2bf(float f) {
    union { float f; unsigned u; } v; v.f = f;
    unsigned r = (v.u + 0x7FFFu + ((v.u >> 16) & 1u)) >> 16;
    return (unsigned short)r;
}

// ---------------------------------------------------------------------------
// Tiled fp32 GEMM: C = A[M,K] @ W[K,N] (+ bias).  (unchanged from round 0)
// LAYOUT 0: C row-major [M,N];  LAYOUT 1: scatter to [B,H,S,HD]
// ---------------------------------------------------------------------------
template<int LAYOUT>
__global__ __launch_bounds__(256) void gemm_f32_64x64(
    const float* __restrict__ A, const float* __restrict__ W,
    const float* __restrict__ bias, float* __restrict__ C,
    int M, int N, int K)
{
    const int bm = blockIdx.x;
    const int bn = blockIdx.y;
    const int tid = threadIdx.x;
    const int tx = tid & 15;
    const int ty = tid >> 4;

    __shared__ float As[64][17];
    __shared__ float Bs[16][64];

    float acc[4][4] = {};

    const int m0 = bm * 64;
    const int n0 = bn * 64;

    for (int k0 = 0; k0 < K; k0 += 16) {
        {
            const int r = tid >> 2;
            const int c = (tid & 3) * 4;
            const float4 v = *reinterpret_cast<const float4*>(
                &A[(size_t)(m0 + r) * K + k0 + c]);
            As[r][c + 0] = v.x; As[r][c + 1] = v.y;
            As[r][c + 2] = v.z; As[r][c + 3] = v.w;
        }
        {
            const int r = tid >> 4;
            const int c = (tid & 15) * 4;
            const float4 v = *reinterpret_cast<const float4*>(
                &W[(size_t)(k0 + r) * N + n0 + c]);
            *reinterpret_cast<float4*>(&Bs[r][c]) = v;
        }
        __syncthreads();
        #pragma unroll
        for (int kk = 0; kk < 16; ++kk) {
            float a[4], b[4];
            #pragma unroll
            for (int i = 0; i < 4; ++i) a[i] = As[ty * 4 + i][kk];
            #pragma unroll
            for (int j = 0; j < 4; ++j) b[j] = Bs[kk][tx * 4 + j];
            #pragma unroll
            for (int i = 0; i < 4; ++i)
                #pragma unroll
                for (int j = 0; j < 4; ++j)
                    acc[i][j] += a[i] * b[j];
        }
        __syncthreads();
    }

    #pragma unroll
    for (int i = 0; i < 4; ++i) {
        const int m = m0 + ty * 4 + i;
        #pragma unroll
        for (int j = 0; j < 4; ++j) {
            const int n = n0 + tx * 4 + j;
            float v = acc[i][j];
            if (bias) v += bias[n];
            if (LAYOUT == 0) {
                C[(size_t)m * N + n] = v;
            } else {
                const int b_ = m / SS, s_ = m % SS;
                const int h_ = n / HDD, d_ = n % HDD;
                C[(((size_t)(b_ * HH + h_) * SS) + s_) * HDD + d_] = v;
            }
        }
    }
}

// ---------------------------------------------------------------------------
// MFMA flash attention, bf16 compute / fp32 softmax state.
// Q,K,V fp32 in [B,H,S,HD]; Out fp32 in [B,S,D].
// Block: 256 thr = 4 waves; block processes q-tile pair {qp, 31-qp} (64 rows
// each) for one (b,h) -> uniform 33 KV-tiles of work per block.
// Wave w owns q-rows w*16..w*16+15 of the current 64-row q-tile.
// mfma_f32_16x16x32_bf16:
//   A-frag: lane l holds A[l&15][8*(l>>4)+t], t=0..7 (contiguous k)
//   B-frag: lane l holds B[8*(l>>4)+t][l&15]
//   C/D  : lane l holds C[(l>>4)*4+r][l&15]          (m89-verified)
// LDS row stride 76 elems (152 B) + b64 fragment loads -> near-conflict-free.
// ---------------------------------------------------------------------------
#define LDST 76

__global__ __launch_bounds__(256) void attn_mfma_bf16(
    const float* __restrict__ Q, const float* __restrict__ K,
    const float* __restrict__ V, float* __restrict__ Out)
{
    const int qp = blockIdx.x;            // 0..15 (q-tile pair)
    const int bh = blockIdx.y;            // 0..31
    const int b  = bh >> 4, h = bh & 15;
    const int tid  = threadIdx.x;
    const int w    = tid >> 6;            // wave 0..3
    const int lane = tid & 63;
    const int c    = lane & 15;           // fragment col / row-in-16
    const int g    = lane >> 4;           // lane group 0..3

    __shared__ unsigned short Ks[64][LDST];          // K tile (also Q staging)
    __shared__ unsigned short Vt[64][LDST];          // V tile, transposed [d][j]
    __shared__ unsigned short Pw[4][16][LDST];       // per-wave P tile

    const float slope = exp2f(-0.5f * (float)(h + 1));  // 2^(-8*(h+1)/16)
    const float scale = 0.125f;                          // 1/sqrt(64)

    const int srow = tid >> 2;            // staging: row 0..63
    const int scol = (tid & 3) * 4;       // staging: col base

    #pragma unroll 1
    for (int qsel = 0; qsel < 2; ++qsel) {
        const int qt = qsel ? (SS / 64 - 1 - qp) : qp;
        const size_t baseQ = ((size_t)bh * SS + (size_t)qt * 64) * HDD;

        __syncthreads();   // previous q-tile's LDS reads complete
        // ---- stage Q (bf16) into Ks ----
        #pragma unroll
        for (int it = 0; it < 4; ++it) {
            const int col = scol + 16 * it;
            const float4 v = *reinterpret_cast<const float4*>(
                &Q[baseQ + (size_t)srow * HDD + col]);
            short4v pk;
            pk[0] = (short)f2bf(v.x); pk[1] = (short)f2bf(v.y);
            pk[2] = (short)f2bf(v.z); pk[3] = (short)f2bf(v.w);
            *reinterpret_cast<short4v*>(&Ks[srow][col]) = pk;
        }
        __syncthreads();

        // ---- Q fragments (2 k-steps) into registers ----
        short8v qf[2];
        {
            const int qrow = w * 16 + c;
            #pragma unroll
            for (int ks = 0; ks < 2; ++ks) {
                short4v lo = *reinterpret_cast<const short4v*>(&Ks[qrow][32 * ks + 8 * g]);
                short4v hi = *reinterpret_cast<const short4v*>(&Ks[qrow][32 * ks + 8 * g + 4]);
                short8v f = {lo[0], lo[1], lo[2], lo[3], hi[0], hi[1], hi[2], hi[3]};
                qf[ks] = f;
            }
        }

        float m_[4], l_[4];
        f32x4 o_[4];
        #pragma unroll
        for (int r = 0; r < 4; ++r) { m_[r] = -3.0e38f; l_[r] = 0.0f; }
        #pragma unroll
        for (int js = 0; js < 4; ++js) o_[js] = f32x4{0.f, 0.f, 0.f, 0.f};

        for (int kt = 0; kt <= qt; ++kt) {
            __syncthreads();   // prior tile's frag reads (and qf reads) done
            // ---- stage K row-major, V transposed ----
            const size_t baseK = ((size_t)bh * SS + (size_t)kt * 64) * HDD;
            #pragma unroll
            for (int it = 0; it < 4; ++it) {
                const int col = scol + 16 * it;
                const float4 vk = *reinterpret_cast<const float4*>(
                    &K[baseK + (size_t)srow * HDD + col]);
                short4v pk;
                pk[0] = (short)f2bf(vk.x); pk[1] = (short)f2bf(vk.y);
                pk[2] = (short)f2bf(vk.z); pk[3] = (short)f2bf(vk.w);
                *reinterpret_cast<short4v*>(&Ks[srow][col]) = pk;
                const float4 vv = *reinterpret_cast<const float4*>(
                    &V[baseK + (size_t)srow * HDD + col]);
                Vt[col + 0][srow] = f2bf(vv.x);
                Vt[col + 1][srow] = f2bf(vv.y);
                Vt[col + 2][srow] = f2bf(vv.z);
                Vt[col + 3][srow] = f2bf(vv.w);
            }
            __syncthreads();

            // ---- QK^T: 4 j-subtiles x 2 k-steps ----
            f32x4 acc[4];
            #pragma unroll
            for (int js = 0; js < 4; ++js) {
                f32x4 a = {0.f, 0.f, 0.f, 0.f};
                const int krow = js * 16 + c;
                #pragma unroll
                for (int ks = 0; ks < 2; ++ks) {
                    short4v lo = *reinterpret_cast<const short4v*>(&Ks[krow][32 * ks + 8 * g]);
                    short4v hi = *reinterpret_cast<const short4v*>(&Ks[krow][32 * ks + 8 * g + 4]);
                    short8v kf = {lo[0], lo[1], lo[2], lo[3], hi[0], hi[1], hi[2], hi[3]};
                    a = __builtin_amdgcn_mfma_f32_16x16x32_bf16(qf[ks], kf, a, 0, 0, 0);
                }
                acc[js] = a;
            }

            // ---- scale + ALiBi + causal mask (diag tile only) ----
            float s[4][4];   // [js][r]
            const int jb = kt * 64 + c;
            const bool diag = (kt == qt);
            const int iloc = w * 16 + 4 * g;   // + r
            #pragma unroll
            for (int js = 0; js < 4; ++js) {
                const float ab = slope * (float)(jb + 16 * js);
                #pragma unroll
                for (int r = 0; r < 4; ++r) {
                    float val = acc[js][r] * scale - ab;
                    if (diag && (16 * js + c) > (iloc + r)) val = -3.0e38f;
                    s[js][r] = val;
                }
            }

            // ---- online softmax (reduce over 16-lane groups) ----
            float corr[4];
            #pragma unroll
            for (int r = 0; r < 4; ++r) {
                float mr = fmaxf(fmaxf(s[0][r], s[1][r]), fmaxf(s[2][r], s[3][r]));
                #pragma unroll
                for (int off = 8; off; off >>= 1)
                    mr = fmaxf(mr, __shfl_xor(mr, off, 64));
                const float mn = fmaxf(m_[r], mr);
                corr[r] = __expf(m_[r] - mn);
                m_[r] = mn;
            }
            float rs[4] = {0.f, 0.f, 0.f, 0.f};
            #pragma unroll
            for (int js = 0; js < 4; ++js) {
                #pragma unroll
                for (int r = 0; r < 4; ++r) {
                    const float p = __expf(s[js][r] - m_[r]);
                    rs[r] += p;
                    Pw[w][4 * g + r][js * 16 + c] = f2bf(p);
                }
            }
            #pragma unroll
            for (int r = 0; r < 4; ++r) {
                #pragma unroll
                for (int off = 8; off; off >>= 1)
                    rs[r] += __shfl_xor(rs[r], off, 64);
                l_[r] = l_[r] * corr[r] + rs[r];
            }
            #pragma unroll
            for (int js = 0; js < 4; ++js) {
                #pragma unroll
                for (int r = 0; r < 4; ++r) o_[js][r] *= corr[r];
            }

            // wave-local: make P writes visible to own lanes
            asm volatile("s_waitcnt lgkmcnt(0)" ::: "memory");

            // ---- P fragments, then PV ----
            short8v pf[2];
            #pragma unroll
            for (int ks = 0; ks < 2; ++ks) {
                short4v lo = *reinterpret_cast<const short4v*>(&Pw[w][c][32 * ks + 8 * g]);
                short4v hi = *reinterpret_cast<const short4v*>(&Pw[w][c][32 * ks + 8 * g + 4]);
                short8v f = {lo[0], lo[1], lo[2], lo[3], hi[0], hi[1], hi[2], hi[3]};
                pf[ks] = f;
            }
            #pragma unroll
            for (int js = 0; js < 4; ++js) {
                const int vrow = js * 16 + c;
                #pragma unroll
                for (int ks = 0; ks < 2; ++ks) {
                    short4v lo = *reinterpret_cast<const short4v*>(&Vt[vrow][32 * ks + 8 * g]);
                    short4v hi = *reinterpret_cast<const short4v*>(&Vt[vrow][32 * ks + 8 * g + 4]);
                    short8v vf = {lo[0], lo[1], lo[2], lo[3], hi[0], hi[1], hi[2], hi[3]};
                    o_[js] = __builtin_amdgcn_mfma_f32_16x16x32_bf16(pf[ks], vf, o_[js], 0, 0, 0);
                }
            }
        }

        // ---- normalize + write [B,S,D] ----
        float inv[4];
        #pragma unroll
        for (int r = 0; r < 4; ++r) inv[r] = 1.0f / l_[r];
        const size_t baseO = ((size_t)b * SS + (size_t)qt * 64 + w * 16) * DD + h * HDD;
        #pragma unroll
        for (int js = 0; js < 4; ++js) {
            #pragma unroll
            for (int r = 0; r < 4; ++r) {
                Out[baseO + (size_t)(4 * g + r) * DD + js * 16 + c] = o_[js][r] * inv[r];
            }
        }
    }
}

// ---------------------------------------------------------------------------
extern "C" void kernel_launch(void* const* d_in, const int* in_sizes, int n_in,
                              void* d_out, int out_size, void* d_ws, size_t ws_size,
                              hipStream_t stream) {
    const float* x  = (const float*)d_in[0];
    const float* Wq = (const float*)d_in[1];
    const float* bq = (const float*)d_in[2];
    const float* Wk = (const float*)d_in[3];
    const float* bk = (const float*)d_in[4];
    const float* Wv = (const float*)d_in[5];
    const float* Wo = (const float*)d_in[6];
    const float* bo = (const float*)d_in[7];
    float* out = (float*)d_out;

    const size_t per = (size_t)BB * HH * SS * HDD;
    float* Qb   = (float*)d_ws;
    float* Kb   = Qb + per;
    float* Vb   = Kb + per;
    float* attn = Vb + per;   // [B,S,D]

    const dim3 blk(256);
    const dim3 gProj(BB * SS / 64, DD / 64);

    gemm_f32_64x64<1><<<gProj, blk, 0, stream>>>(x, Wq, bq,      Qb, BB * SS, DD, DD);
    gemm_f32_64x64<1><<<gProj, blk, 0, stream>>>(x, Wk, bk,      Kb, BB * SS, DD, DD);
    gemm_f32_64x64<1><<<gProj, blk, 0, stream>>>(x, Wv, nullptr, Vb, BB * SS, DD, DD);

    const dim3 gAttn(SS / 128, BB * HH);   // 16 q-pairs x 32 (b,h)
    attn_mfma_bf16<<<gAttn, blk, 0, stream>>>(Qb, Kb, Vb, attn);

    gemm_f32_64x64<0><<<gProj, blk, 0, stream>>>(attn, Wo, bo, out, BB * SS, DD, DD);
}

// Round 4
// 234.104 us; speedup vs baseline: 7.5251x; 3.1313x over previous
//
#include <hip/hip_runtime.h>
#include <math.h>

#define BB 2
#define SS 2048
#define DD 1024
#define HH 16
#define HDD 64

typedef __attribute__((ext_vector_type(4))) short short4v;
typedef __attribute__((ext_vector_type(8))) short short8v;
typedef __attribute__((ext_vector_type(4))) unsigned short ushort4v;
typedef __attribute__((ext_vector_type(8))) unsigned short ushort8v;
typedef __attribute__((ext_vector_type(4))) float f32x4;

__device__ __forceinline__ unsigned short f2bf(float f) {
    union { float f; unsigned u; } v; v.f = f;
    return (unsigned short)((v.u + 0x7FFFu + ((v.u >> 16) & 1u)) >> 16);
}

__device__ __forceinline__ void gload_lds16(const void* g, void* l) {
    __builtin_amdgcn_global_load_lds(
        (const __attribute__((address_space(1))) void*)g,
        (__attribute__((address_space(3))) void*)l, 16, 0, 0);
}

// ---------------------------------------------------------------------------
// fp32 -> bf16 convert of x [4096*1024]
// ---------------------------------------------------------------------------
__global__ __launch_bounds__(256) void convert_x(const float* __restrict__ x,
                                                 unsigned short* __restrict__ xb) {
    const size_t i = ((size_t)blockIdx.x * 256 + threadIdx.x) * 8;
    const float4 a = *(const float4*)&x[i];
    const float4 b = *(const float4*)&x[i + 4];
    ushort8v o;
    o[0] = f2bf(a.x); o[1] = f2bf(a.y); o[2] = f2bf(a.z); o[3] = f2bf(a.w);
    o[4] = f2bf(b.x); o[5] = f2bf(b.y); o[6] = f2bf(b.z); o[7] = f2bf(b.w);
    *(ushort8v*)&xb[i] = o;
}

// ---------------------------------------------------------------------------
// Transpose+convert weights: Wt[n][k] = bf16(W[k][n]), 1024x1024, z = matrix.
// ---------------------------------------------------------------------------
__global__ __launch_bounds__(256) void transpose_w(
    const float* __restrict__ W0, const float* __restrict__ W1,
    const float* __restrict__ W2, const float* __restrict__ W3,
    unsigned short* __restrict__ T0, unsigned short* __restrict__ T1,
    unsigned short* __restrict__ T2, unsigned short* __restrict__ T3) {
    const int z = blockIdx.z;
    const float* W = z == 0 ? W0 : z == 1 ? W1 : z == 2 ? W2 : W3;
    unsigned short* T = z == 0 ? T0 : z == 1 ? T1 : z == 2 ? T2 : T3;
    const int k0 = blockIdx.x * 64, n0 = blockIdx.y * 64;
    const int tid = threadIdx.x;
    __shared__ unsigned short tt[64][65];
    const int rr = tid >> 4, cc = (tid & 15) * 4;
    #pragma unroll
    for (int it = 0; it < 4; ++it) {
        const int r = it * 16 + rr;
        const float4 v = *(const float4*)&W[(size_t)(k0 + r) * DD + n0 + cc];
        tt[r][cc + 0] = f2bf(v.x); tt[r][cc + 1] = f2bf(v.y);
        tt[r][cc + 2] = f2bf(v.z); tt[r][cc + 3] = f2bf(v.w);
    }
    __syncthreads();
    #pragma unroll
    for (int it = 0; it < 4; ++it) {
        const int n = it * 16 + rr;
        ushort4v o;
        o[0] = tt[cc + 0][n]; o[1] = tt[cc + 1][n];
        o[2] = tt[cc + 2][n]; o[3] = tt[cc + 3][n];
        *(ushort4v*)&T[(size_t)(n0 + n) * DD + k0 + cc] = o;
    }
}

// ---------------------------------------------------------------------------
// bf16 MFMA GEMM, m97 structure: BM=128, BK=32, global_load_lds staging,
// Wt stored [N][K] so both A and B tiles stage linearly and fragments are
// contiguous ds_read_b128.  4 waves in 2x2; wave tile 64 x (NF*16).
// MODE 0: fused QKV (gridDim.y = 24, virtual N=3072), bf16 out scattered to
//         [B,H,S,HD] with fp32 bias for Q,K.
// MODE 1: out-proj (NF=2, BN=64), fp32 out [M,N] + bias.
// ---------------------------------------------------------------------------
template<int MODE, int NF>
__global__ __launch_bounds__(256) void gemm_bf16(
    const unsigned short* __restrict__ A,
    const unsigned short* __restrict__ Wt0, const unsigned short* __restrict__ Wt1,
    const unsigned short* __restrict__ Wt2,
    const float* __restrict__ bias0, const float* __restrict__ bias1,
    unsigned short* __restrict__ O0, unsigned short* __restrict__ O1,
    unsigned short* __restrict__ O2,
    float* __restrict__ Of, const float* __restrict__ biasf)
{
    constexpr int BN = NF * 32;
    const int tid = threadIdx.x;
    const int w = tid >> 6, lane = tid & 63;
    const int wm = w >> 1, wn = w & 1;
    const int c = lane & 15, g = lane >> 4;
    const int m0 = blockIdx.x * 128;

    const unsigned short* Wsel;
    int nn0, mat = 0;
    if (MODE == 0) {
        const int by = blockIdx.y;           // 0..23
        mat = by >> 3;
        nn0 = (by & 7) * 128;
        Wsel = mat == 0 ? Wt0 : mat == 1 ? Wt1 : Wt2;
    } else {
        nn0 = blockIdx.y * BN;
        Wsel = Wt0;
    }

    __shared__ alignas(16) unsigned short As[128 * 32];
    __shared__ alignas(16) unsigned short Bs[BN * 32];

    f32x4 acc[4][NF];
    #pragma unroll
    for (int mf = 0; mf < 4; ++mf)
        #pragma unroll
        for (int nf = 0; nf < NF; ++nf) acc[mf][nf] = f32x4{0.f, 0.f, 0.f, 0.f};

    const int lr = lane >> 2;          // 0..15
    const int lc8 = (lane & 3) * 8;    // 0,8,16,24

    for (int kt = 0; kt < DD; kt += 32) {
        #pragma unroll
        for (int i = 0; i < 2; ++i) {
            const int ii = w * 2 + i;
            gload_lds16(&A[(size_t)(m0 + ii * 16 + lr) * DD + kt + lc8], &As[ii * 512]);
        }
        if (NF == 4) {
            #pragma unroll
            for (int i = 0; i < 2; ++i) {
                const int ii = w * 2 + i;
                gload_lds16(&Wsel[(size_t)(nn0 + ii * 16 + lr) * DD + kt + lc8], &Bs[ii * 512]);
            }
        } else {
            gload_lds16(&Wsel[(size_t)(nn0 + w * 16 + lr) * DD + kt + lc8], &Bs[w * 512]);
        }
        __syncthreads();

        short8v a[4], bfr[NF];
        #pragma unroll
        for (int mf = 0; mf < 4; ++mf)
            a[mf] = *(const short8v*)&As[(wm * 64 + mf * 16 + c) * 32 + 8 * g];
        #pragma unroll
        for (int nf = 0; nf < NF; ++nf)
            bfr[nf] = *(const short8v*)&Bs[(wn * (NF * 16) + nf * 16 + c) * 32 + 8 * g];
        #pragma unroll
        for (int mf = 0; mf < 4; ++mf)
            #pragma unroll
            for (int nf = 0; nf < NF; ++nf)
                acc[mf][nf] = __builtin_amdgcn_mfma_f32_16x16x32_bf16(
                    a[mf], bfr[nf], acc[mf][nf], 0, 0, 0);
        __syncthreads();
    }

    if (MODE == 0) {
        unsigned short* Odst = mat == 0 ? O0 : mat == 1 ? O1 : O2;
        const float* bp = mat == 0 ? bias0 : mat == 1 ? bias1 : nullptr;
        #pragma unroll
        for (int nf = 0; nf < NF; ++nf) {
            const int nl = nn0 + wn * 64 + nf * 16 + c;      // col within matrix
            const int h = nl >> 6, hd = nl & 63;
            const float bv = bp ? bp[nl] : 0.0f;
            #pragma unroll
            for (int mf = 0; mf < 4; ++mf)
                #pragma unroll
                for (int r = 0; r < 4; ++r) {
                    const int m = m0 + wm * 64 + mf * 16 + 4 * g + r;
                    const int b_ = m >> 11, s_ = m & (SS - 1);
                    Odst[(((size_t)(b_ * HH + h) * SS) + s_) * HDD + hd] =
                        f2bf(acc[mf][nf][r] + bv);
                }
        }
    } else {
        #pragma unroll
        for (int nf = 0; nf < NF; ++nf) {
            const int n = nn0 + wn * (NF * 16) + nf * 16 + c;
            const float bv = biasf[n];
            #pragma unroll
            for (int mf = 0; mf < 4; ++mf)
                #pragma unroll
                for (int r = 0; r < 4; ++r) {
                    const int m = m0 + wm * 64 + mf * 16 + 4 * g + r;
                    Of[(size_t)m * DD + n] = acc[mf][nf][r] + bv;
                }
        }
    }
}

// ---------------------------------------------------------------------------
// MFMA flash attention, all-bf16 I/O.  Q,K,V bf16 [B,H,S,HD]; Out bf16 [B,S,D].
// Same verified structure as round 1; Q frags now loaded direct global->reg;
// XCD-swizzled 1-D grid so blocks sharing (b,h) share an XCD L2.
// ---------------------------------------------------------------------------
#define LDST 76

__global__ __launch_bounds__(256) void attn_mfma_bf16(
    const unsigned short* __restrict__ Q, const unsigned short* __restrict__ K,
    const unsigned short* __restrict__ V, unsigned short* __restrict__ Out)
{
    const int lin  = blockIdx.x;           // 0..511
    const int xcd  = lin & 7;
    const int rest = lin >> 3;
    const int qp   = rest & 15;
    const int bh   = xcd + 8 * (rest >> 4);
    const int b = bh >> 4, h = bh & 15;
    const int tid  = threadIdx.x;
    const int w    = tid >> 6;
    const int lane = tid & 63;
    const int c    = lane & 15;
    const int g    = lane >> 4;

    __shared__ unsigned short Ks[64][LDST];
    __shared__ unsigned short Vt[64][LDST];
    __shared__ unsigned short Pw[4][16][LDST];

    const float slope = exp2f(-0.5f * (float)(h + 1));
    const float scale = 0.125f;

    const int srow = tid >> 2;
    const int scol = (tid & 3) * 16;

    #pragma unroll 1
    for (int qsel = 0; qsel < 2; ++qsel) {
        const int qt = qsel ? (SS / 64 - 1 - qp) : qp;
        const size_t baseQ = ((size_t)bh * SS + (size_t)qt * 64) * HDD;

        // Q fragments direct from global (bf16)
        short8v qf[2];
        {
            const size_t qrow = baseQ + (size_t)(w * 16 + c) * HDD;
            qf[0] = *(const short8v*)&Q[qrow + 8 * g];
            qf[1] = *(const short8v*)&Q[qrow + 32 + 8 * g];
        }

        float m_[4], l_[4];
        f32x4 o_[4];
        #pragma unroll
        for (int r = 0; r < 4; ++r) { m_[r] = -3.0e38f; l_[r] = 0.0f; }
        #pragma unroll
        for (int js = 0; js < 4; ++js) o_[js] = f32x4{0.f, 0.f, 0.f, 0.f};

        for (int kt = 0; kt <= qt; ++kt) {
            __syncthreads();   // prior tile's LDS reads complete
            const size_t baseK = ((size_t)bh * SS + (size_t)kt * 64) * HDD;
            {
                const size_t rb = baseK + (size_t)srow * HDD + scol;
                const ushort8v k0 = *(const ushort8v*)&K[rb];
                const ushort8v k1 = *(const ushort8v*)&K[rb + 8];
                ushort4v t;
                t[0]=k0[0]; t[1]=k0[1]; t[2]=k0[2]; t[3]=k0[3];
                *(ushort4v*)&Ks[srow][scol]      = t;
                t[0]=k0[4]; t[1]=k0[5]; t[2]=k0[6]; t[3]=k0[7];
                *(ushort4v*)&Ks[srow][scol + 4]  = t;
                t[0]=k1[0]; t[1]=k1[1]; t[2]=k1[2]; t[3]=k1[3];
                *(ushort4v*)&Ks[srow][scol + 8]  = t;
                t[0]=k1[4]; t[1]=k1[5]; t[2]=k1[6]; t[3]=k1[7];
                *(ushort4v*)&Ks[srow][scol + 12] = t;
                const ushort8v v0 = *(const ushort8v*)&V[rb];
                const ushort8v v1 = *(const ushort8v*)&V[rb + 8];
                #pragma unroll
                for (int t2 = 0; t2 < 8; ++t2) {
                    Vt[scol + t2][srow]     = v0[t2];
                    Vt[scol + 8 + t2][srow] = v1[t2];
                }
            }
            __syncthreads();

            // QK^T
            f32x4 acc[4];
            #pragma unroll
            for (int js = 0; js < 4; ++js) {
                f32x4 a = {0.f, 0.f, 0.f, 0.f};
                const int krow = js * 16 + c;
                #pragma unroll
                for (int ks = 0; ks < 2; ++ks) {
                    short4v lo = *(const short4v*)&Ks[krow][32 * ks + 8 * g];
                    short4v hi = *(const short4v*)&Ks[krow][32 * ks + 8 * g + 4];
                    short8v kf = {lo[0], lo[1], lo[2], lo[3], hi[0], hi[1], hi[2], hi[3]};
                    a = __builtin_amdgcn_mfma_f32_16x16x32_bf16(qf[ks], kf, a, 0, 0, 0);
                }
                acc[js] = a;
            }

            // scale + ALiBi + causal mask
            float s[4][4];
            const int jb = kt * 64 + c;
            const bool diag = (kt == qt);
            const int iloc = w * 16 + 4 * g;
            #pragma unroll
            for (int js = 0; js < 4; ++js) {
                const float ab = slope * (float)(jb + 16 * js);
                #pragma unroll
                for (int r = 0; r < 4; ++r) {
                    float val = acc[js][r] * scale - ab;
                    if (diag && (16 * js + c) > (iloc + r)) val = -3.0e38f;
                    s[js][r] = val;
                }
            }

            // online softmax
            float corr[4];
            #pragma unroll
            for (int r = 0; r < 4; ++r) {
                float mr = fmaxf(fmaxf(s[0][r], s[1][r]), fmaxf(s[2][r], s[3][r]));
                #pragma unroll
                for (int off = 8; off; off >>= 1)
                    mr = fmaxf(mr, __shfl_xor(mr, off, 64));
                const float mn = fmaxf(m_[r], mr);
                corr[r] = __expf(m_[r] - mn);
                m_[r] = mn;
            }
            float rs[4] = {0.f, 0.f, 0.f, 0.f};
            #pragma unroll
            for (int js = 0; js < 4; ++js) {
                #pragma unroll
                for (int r = 0; r < 4; ++r) {
                    const float p = __expf(s[js][r] - m_[r]);
                    rs[r] += p;
                    Pw[w][4 * g + r][js * 16 + c] = f2bf(p);
                }
            }
            #pragma unroll
            for (int r = 0; r < 4; ++r) {
                #pragma unroll
                for (int off = 8; off; off >>= 1)
                    rs[r] += __shfl_xor(rs[r], off, 64);
                l_[r] = l_[r] * corr[r] + rs[r];
            }
            #pragma unroll
            for (int js = 0; js < 4; ++js) {
                #pragma unroll
                for (int r = 0; r < 4; ++r) o_[js][r] *= corr[r];
            }

            asm volatile("s_waitcnt lgkmcnt(0)" ::: "memory");

            // PV
            short8v pf[2];
            #pragma unroll
            for (int ks = 0; ks < 2; ++ks) {
                short4v lo = *(const short4v*)&Pw[w][c][32 * ks + 8 * g];
                short4v hi = *(const short4v*)&Pw[w][c][32 * ks + 8 * g + 4];
                short8v f = {lo[0], lo[1], lo[2], lo[3], hi[0], hi[1], hi[2], hi[3]};
                pf[ks] = f;
            }
            #pragma unroll
            for (int js = 0; js < 4; ++js) {
                const int vrow = js * 16 + c;
                #pragma unroll
                for (int ks = 0; ks < 2; ++ks) {
                    short4v lo = *(const short4v*)&Vt[vrow][32 * ks + 8 * g];
                    short4v hi = *(const short4v*)&Vt[vrow][32 * ks + 8 * g + 4];
                    short8v vf = {lo[0], lo[1], lo[2], lo[3], hi[0], hi[1], hi[2], hi[3]};
                    o_[js] = __builtin_amdgcn_mfma_f32_16x16x32_bf16(pf[ks], vf, o_[js], 0, 0, 0);
                }
            }
        }

        // write bf16 [B,S,D]
        float inv[4];
        #pragma unroll
        for (int r = 0; r < 4; ++r) inv[r] = 1.0f / l_[r];
        const size_t baseO = ((size_t)b * SS + (size_t)qt * 64 + w * 16) * DD + h * HDD;
        #pragma unroll
        for (int js = 0; js < 4; ++js) {
            #pragma unroll
            for (int r = 0; r < 4; ++r) {
                Out[baseO + (size_t)(4 * g + r) * DD + js * 16 + c] =
                    f2bf(o_[js][r] * inv[r]);
            }
        }
    }
}

// ---------------------------------------------------------------------------
extern "C" void kernel_launch(void* const* d_in, const int* in_sizes, int n_in,
                              void* d_out, int out_size, void* d_ws, size_t ws_size,
                              hipStream_t stream) {
    const float* x  = (const float*)d_in[0];
    const float* Wq = (const float*)d_in[1];
    const float* bq = (const float*)d_in[2];
    const float* Wk = (const float*)d_in[3];
    const float* bk = (const float*)d_in[4];
    const float* Wv = (const float*)d_in[5];
    const float* Wo = (const float*)d_in[6];
    const float* bo = (const float*)d_in[7];

    unsigned short* ws = (unsigned short*)d_ws;
    unsigned short* xb    = ws;                   // 4M elems (8MB)
    unsigned short* Wqt   = xb + 4194304;         // 1M each
    unsigned short* Wkt   = Wqt + 1048576;
    unsigned short* Wvt   = Wkt + 1048576;
    unsigned short* Wot   = Wvt + 1048576;
    unsigned short* Qb    = Wot + 1048576;        // 4M each
    unsigned short* Kb    = Qb + 4194304;
    unsigned short* Vb    = Kb + 4194304;
    unsigned short* attnb = Vb + 4194304;

    convert_x<<<2048, 256, 0, stream>>>(x, xb);
    transpose_w<<<dim3(16, 16, 4), 256, 0, stream>>>(Wq, Wk, Wv, Wo,
                                                     Wqt, Wkt, Wvt, Wot);

    gemm_bf16<0, 4><<<dim3(32, 24), 256, 0, stream>>>(
        xb, Wqt, Wkt, Wvt, bq, bk, Qb, Kb, Vb, nullptr, nullptr);

    attn_mfma_bf16<<<512, 256, 0, stream>>>(Qb, Kb, Vb, attnb);

    gemm_bf16<1, 2><<<dim3(32, 16), 256, 0, stream>>>(
        attnb, Wot, nullptr, nullptr, nullptr, nullptr,
        nullptr, nullptr, nullptr, (float*)d_out, bo);
}